// Round 6
// baseline (2232.868 us; speedup 1.0000x reference)
//
#include <hip/hip_runtime.h>
#include <hip/hip_bf16.h>
#include <stdint.h>

#define B_ 2
#define S_ 2048
#define H_ 1024
#define F_ 4096
#define E_ 8
#define KTOP_ 2
#define NTOK (B_*S_)          // 4096
#define NPAIR (KTOP_*NTOK)    // 8192
#define NPAIR_PAD (NPAIR+256)

// ---- workspace layout (bytes) ----
static const size_t WS_XG   = 131072;
static const size_t SZ_XG   = (size_t)NPAIR_PAD * H_ * 2;
static const size_t WS_W1T  = WS_XG + SZ_XG;
static const size_t SZ_W1T  = (size_t)E_ * F_ * H_ * 2;
static const size_t WS_W2T  = WS_W1T + SZ_W1T;
static const size_t SZ_W2T  = (size_t)E_ * H_ * F_ * 2;
static const size_t WS_HBUF = WS_W2T + SZ_W2T;
static const size_t SZ_HBUF = (size_t)NPAIR_PAD * F_ * 2;
static const size_t WS_YBUF = WS_HBUF + SZ_HBUF;   // 2 z-planes of NPAIR*H f32

typedef __attribute__((ext_vector_type(8))) short bf16x8;
typedef __attribute__((ext_vector_type(4))) float f32x4;

__device__ __forceinline__ unsigned short f2bf(float f) {
  unsigned int u = __float_as_uint(f);
  u += 0x7fffu + ((u >> 16) & 1u);
  return (unsigned short)(u >> 16);
}

__device__ __forceinline__ void load_lds16(const void* g, void* l) {
  __builtin_amdgcn_global_load_lds(
      (const __attribute__((address_space(1))) unsigned int*)g,
      (__attribute__((address_space(3))) unsigned int*)l, 16, 0, 0);
}

// meta ints: [0..7]=counts [8..15]=fill [16..23]=offs [24]=total
// [25]=ntiles256 [32..71]=desc256
__global__ void k_init(int* meta) {
  if (threadIdx.x < 32) meta[threadIdx.x] = 0;
}

__global__ void k_count(const int* __restrict__ sel, int* meta) {
  int i = blockIdx.x * 256 + threadIdx.x;
  if (i < NPAIR) atomicAdd(&meta[sel[i]], 1);
}

__global__ void k_scan(int* meta) {
  if (threadIdx.x == 0) {
    int acc = 0, t256 = 0;
    for (int e = 0; e < E_; e++) {
      meta[16 + e] = acc;
      int c = meta[e];
      for (int r0 = 0; r0 < c; r0 += 256) meta[32 + (t256++)] = (e << 13) | r0;
      acc += c;
    }
    meta[24] = acc;
    meta[25] = t256;
  }
}

__global__ void k_fill(const int* __restrict__ sel, const float* __restrict__ probs,
                       int* meta, int* __restrict__ tok, int* __restrict__ slot,
                       float* __restrict__ prob) {
  int i = blockIdx.x * 256 + threadIdx.x;
  if (i < NPAIR) {
    int e = sel[i];
    int pos = meta[16 + e] + atomicAdd(&meta[8 + e], 1);
    tok[pos]  = i & (NTOK - 1);
    slot[pos] = i;
    prob[pos] = probs[i];
  }
}

__global__ void k_gather(const float* __restrict__ x, const int* __restrict__ tok,
                         unsigned short* __restrict__ Xg) {
  int p = blockIdx.x, t = threadIdx.x;
  int token = tok[p];
  float4 v = ((const float4*)(x + (size_t)token * H_))[t];
  ushort4 o;
  o.x = f2bf(v.x); o.y = f2bf(v.y); o.z = f2bf(v.z); o.w = f2bf(v.w);
  ((ushort4*)(Xg + (size_t)p * H_))[t] = o;
}

// src [E][R][C] f32 -> dst [E][C][R] bf16.  64x64 tiles, coalesced ushort2 writes.
__global__ void k_transpose(const float* __restrict__ src, unsigned short* __restrict__ dst,
                            int R, int C) {
  __shared__ float tile[64][65];
  int e = blockIdx.z;
  size_t c0 = (size_t)blockIdx.x * 64, r0 = (size_t)blockIdx.y * 64;
  int t = threadIdx.x;
  int r = t >> 2, q = t & 3;
  const float4* s = (const float4*)(src + ((size_t)e * R + r0 + r) * C + c0 + q * 16);
  float4 v0 = s[0], v1 = s[1], v2 = s[2], v3 = s[3];
  float* tp = &tile[r][q * 16];
  tp[0]=v0.x; tp[1]=v0.y; tp[2]=v0.z; tp[3]=v0.w;
  tp[4]=v1.x; tp[5]=v1.y; tp[6]=v1.z; tp[7]=v1.w;
  tp[8]=v2.x; tp[9]=v2.y; tp[10]=v2.z; tp[11]=v2.w;
  tp[12]=v3.x; tp[13]=v3.y; tp[14]=v3.z; tp[15]=v3.w;
  __syncthreads();
  unsigned short* d = dst + ((size_t)e * C + c0) * R + r0;
#pragma unroll
  for (int i = 0; i < 8; i++) {
    int chunk = t + 256 * i;           // 0..2047
    int c = chunk >> 5, j = chunk & 31;
    ushort2 o;
    o.x = f2bf(tile[2 * j][c]);
    o.y = f2bf(tile[2 * j + 1][c]);
    *(ushort2*)(d + (size_t)c * R + 2 * j) = o;
  }
}

__device__ __forceinline__ float gelu_f(float x) {
  float x2 = x * x;
  float ttt = x * (2.302118f + 0.1029518f * x2);
  ttt = fminf(ttt, 60.f);
  float u = __builtin_amdgcn_exp2f(ttt);
  float rr = __frcp_rn(1.f + u);
  return x * u * rr;
}

// -------- 256x256 grouped GEMM, BK=32 dbuf (64 KB LDS -> 2 blk/CU) ----------
// Loop (proven round-5 structure): stage(k+1 -> alt); compute(k); sync.
// 512 threads = 8 waves (2M x 4N), per-wave 128x64 (acc[8][4]).
// Flat 1D grid with bijective XCD chunking, x-major (same B col-slice per XCD
// chunk -> B becomes L2-resident).  Swizzle identical to round 5 (verified):
// involution off ^= ((off>>7)&7)<<4, applied to per-lane global source and
// ds_read addrs, linear global_load_lds dest.
// EP0: Hbuf = gelu(acc+b1) bf16.   EP1 (z-split): yplane[z][slot] =
// (acc + (z==0)*b2)*prob, planes combined later.
template <int KROW, int KLEN, int EP>
__global__ __launch_bounds__(512, 4) void k_g256(
    const short* __restrict__ Aall, const short* __restrict__ Wt,
    const float* __restrict__ bias, const int* __restrict__ meta,
    unsigned short* __restrict__ Hbuf, float* __restrict__ ybuf,
    const int* __restrict__ slotA, const float* __restrict__ prob) {
  constexpr int NT = KLEN / 32;
  constexpr int NFULL = (EP == 0) ? F_ : H_;
  constexpr int NTMAX = 40;
  __shared__ __align__(1024) char lds[2][32768];   // [buf][A 16K | B 16K]

  int bid = blockIdx.x;
  int q = gridDim.x >> 3;
  int vid = (bid & 7) * q + (bid >> 3);            // bijective XCD chunking
  int x, y, z, koff;
  if (EP == 0) {
    x = vid / NTMAX; y = vid - x * NTMAX; z = 0; koff = 0;
  } else {
    int x2 = vid / NTMAX; y = vid - x2 * NTMAX;
    x = x2 >> 1; z = x2 & 1; koff = z * KLEN;
  }
  if (y >= meta[25]) return;
  int dsc = meta[32 + y];
  int e = dsc >> 13, r0 = dsc & 8191;
  int ne = meta[e];
  int p0 = meta[16 + e] + r0;
  int n0 = x * 256;
  const char* A0 = (const char*)(Aall + (size_t)p0 * KROW + koff);
  const char* B0 = (const char*)(Wt + ((size_t)e * NFULL + n0) * KROW + koff);

  int t = threadIdx.x, lane = t & 63, wid = t >> 6;
  int wr = wid >> 2, wc = wid & 3, g = lane >> 4, l15 = lane & 15;
  f32x4 acc[8][4] = {};

  auto stage = [&](int kt, char* dst) {
#pragma unroll
    for (int l = 0; l < 2; l++) {      // A: 16 KB
      int off = l * 8192 + t * 16;
      int o2 = off ^ (((off >> 7) & 7) << 4);
      int row = o2 >> 6, cb = o2 & 63;
      load_lds16(A0 + (size_t)row * (KROW * 2) + kt * 64 + cb, dst + off);
    }
#pragma unroll
    for (int l = 0; l < 2; l++) {      // B: 16 KB
      int off = l * 8192 + t * 16;
      int o2 = off ^ (((off >> 7) & 7) << 4);
      int row = o2 >> 6, cb = o2 & 63;
      load_lds16(B0 + (size_t)row * (KROW * 2) + kt * 64 + cb, dst + 16384 + off);
    }
  };

  auto compute = [&](const char* ab) {
    const char* bb = ab + 16384;
    bf16x8 af[8], bf[4];
#pragma unroll
    for (int m = 0; m < 8; m++) {
      int a = (wr * 128 + m * 16 + l15) * 64 + g * 16;
      af[m] = *(const bf16x8*)(ab + (a ^ (((a >> 7) & 7) << 4)));
    }
#pragma unroll
    for (int n = 0; n < 4; n++) {
      int b = (wc * 64 + n * 16 + l15) * 64 + g * 16;
      bf[n] = *(const bf16x8*)(bb + (b ^ (((b >> 7) & 7) << 4)));
    }
    __builtin_amdgcn_s_setprio(1);
#pragma unroll
    for (int m = 0; m < 8; m++)
#pragma unroll
      for (int n = 0; n < 4; n++)
        acc[m][n] = __builtin_amdgcn_mfma_f32_16x16x32_bf16(af[m], bf[n], acc[m][n], 0, 0, 0);
    __builtin_amdgcn_s_setprio(0);
  };

  stage(0, lds[0]);
  __syncthreads();
  int cur = 0;
  for (int kt = 0; kt < NT; kt++) {
    if (kt + 1 < NT) stage(kt + 1, lds[cur ^ 1]);
    compute(lds[cur]);
    __syncthreads();
    cur ^= 1;
  }

  if (EP == 0) {
#pragma unroll
    for (int n = 0; n < 4; n++) {
      int col = n0 + wc * 64 + n * 16 + l15;
      float bv = bias[e * F_ + col];
#pragma unroll
      for (int m = 0; m < 8; m++) {
        int rbase = wr * 128 + m * 16 + g * 4;
#pragma unroll
        for (int r = 0; r < 4; r++) {
          int row = rbase + r;
          if (r0 + row < ne) {
            float xv = acc[m][n][r] + bv;
            Hbuf[(size_t)(p0 + row) * F_ + col] = f2bf(gelu_f(xv));
          }
        }
      }
    }
  } else {
    float* yplane = ybuf + (size_t)z * NPAIR * H_;
#pragma unroll
    for (int n = 0; n < 4; n++) {
      int col = n0 + wc * 64 + n * 16 + l15;
      float bv = (z == 0) ? bias[e * H_ + col] : 0.f;
#pragma unroll
      for (int m = 0; m < 8; m++) {
        int rbase = wr * 128 + m * 16 + g * 4;
#pragma unroll
        for (int r = 0; r < 4; r++) {
          int row = rbase + r;
          if (r0 + row < ne) {
            int p = p0 + row;
            yplane[(size_t)slotA[p] * H_ + col] = (acc[m][n][r] + bv) * prob[p];
          }
        }
      }
    }
  }
}

__global__ void k_combine(const float* __restrict__ yb, float* __restrict__ out) {
  size_t i = (size_t)blockIdx.x * 256 + threadIdx.x;
  const float4* p00 = (const float4*)yb;                                   // z0,k0
  const float4* p01 = (const float4*)(yb + (size_t)NTOK * H_);             // z0,k1
  const float4* p10 = (const float4*)(yb + (size_t)NPAIR * H_);            // z1,k0
  const float4* p11 = (const float4*)(yb + (size_t)NPAIR * H_ + (size_t)NTOK * H_);
  float4 a = p00[i], b = p01[i], c = p10[i], d = p11[i];
  float4 o;
  o.x = a.x + b.x + c.x + d.x;
  o.y = a.y + b.y + c.y + d.y;
  o.z = a.z + b.z + c.z + d.z;
  o.w = a.w + b.w + c.w + d.w;
  ((float4*)out)[i] = o;
}

extern "C" void kernel_launch(void* const* d_in, const int* in_sizes, int n_in,
                              void* d_out, int out_size, void* d_ws, size_t ws_size,
                              hipStream_t stream) {
  const float* x     = (const float*)d_in[0];
  const float* probs = (const float*)d_in[1];
  const int*   sel   = (const int*)d_in[2];
  const float* w1    = (const float*)d_in[3];
  const float* b1    = (const float*)d_in[4];
  const float* w2    = (const float*)d_in[5];
  const float* b2    = (const float*)d_in[6];
  float* out = (float*)d_out;

  char* W = (char*)d_ws;
  int*   meta = (int*)W;
  int*   tok  = (int*)(W + 4096);
  int*   slot = (int*)(W + 36864);
  float* prob = (float*)(W + 69632);
  unsigned short* Xg  = (unsigned short*)(W + WS_XG);
  short* w1t = (short*)(W + WS_W1T);
  short* w2t = (short*)(W + WS_W2T);
  unsigned short* Hb  = (unsigned short*)(W + WS_HBUF);
  float* yb  = (float*)(W + WS_YBUF);

  k_init<<<1, 256, 0, stream>>>(meta);
  k_count<<<NPAIR / 256, 256, 0, stream>>>(sel, meta);
  k_scan<<<1, 64, 0, stream>>>(meta);
  k_fill<<<NPAIR / 256, 256, 0, stream>>>(sel, probs, meta, tok, slot, prob);
  k_gather<<<NPAIR, 256, 0, stream>>>(x, tok, Xg);
  k_transpose<<<dim3(F_ / 64, H_ / 64, E_), 256, 0, stream>>>(w1, (unsigned short*)w1t, H_, F_);
  k_transpose<<<dim3(H_ / 64, F_ / 64, E_), 256, 0, stream>>>(w2, (unsigned short*)w2t, F_, H_);
  // GEMM1: 256x256, K=1024, flat grid 16 cols x 40 tiles = 640
  k_g256<H_, H_, 0><<<16 * 40, 512, 0, stream>>>(
      (const short*)Xg, w1t, b1, meta, Hb, yb, slot, prob);
  // GEMM2: 256x256, K=4096 z-split in 2 (KLEN=2048), grid 4 cols x 2 z x 40 = 320
  k_g256<F_, F_ / 2, 1><<<4 * 2 * 40, 512, 0, stream>>>(
      (const short*)Hb, w2t, b2, meta, Hb, yb, slot, prob);
  k_combine<<<(NTOK * H_ / 4) / 256, 256, 0, stream>>>(yb, out);
}

// Round 7
// 524.860 us; speedup vs baseline: 4.2542x; 4.2542x over previous
//
#include <hip/hip_runtime.h>
#include <hip/hip_bf16.h>
#include <stdint.h>

#define B_ 2
#define S_ 2048
#define H_ 1024
#define F_ 4096
#define E_ 8
#define KTOP_ 2
#define NTOK (B_*S_)          // 4096
#define NPAIR (KTOP_*NTOK)    // 8192
#define NPAIR_PAD (NPAIR+256)

// ---- workspace layout (bytes) ----
static const size_t WS_XG   = 131072;
static const size_t SZ_XG   = (size_t)NPAIR_PAD * H_ * 2;
static const size_t WS_W1T  = WS_XG + SZ_XG;
static const size_t SZ_W1T  = (size_t)E_ * F_ * H_ * 2;
static const size_t WS_W2T  = WS_W1T + SZ_W1T;
static const size_t SZ_W2T  = (size_t)E_ * H_ * F_ * 2;
static const size_t WS_HBUF = WS_W2T + SZ_W2T;
static const size_t SZ_HBUF = (size_t)NPAIR_PAD * F_ * 2;
static const size_t WS_YBUF = WS_HBUF + SZ_HBUF;   // 2 z-planes of NPAIR*H f32

typedef __attribute__((ext_vector_type(8))) short bf16x8;
typedef __attribute__((ext_vector_type(4))) float f32x4;

__device__ __forceinline__ unsigned short f2bf(float f) {
  unsigned int u = __float_as_uint(f);
  u += 0x7fffu + ((u >> 16) & 1u);
  return (unsigned short)(u >> 16);
}

__device__ __forceinline__ void load_lds16(const void* g, void* l) {
  __builtin_amdgcn_global_load_lds(
      (const __attribute__((address_space(1))) unsigned int*)g,
      (__attribute__((address_space(3))) unsigned int*)l, 16, 0, 0);
}

// meta ints: [0..7]=counts [8..15]=fill [16..23]=offs [24]=total
// [25]=ntiles256 [32..71]=desc256
__global__ void k_init(int* meta) {
  if (threadIdx.x < 32) meta[threadIdx.x] = 0;
}

__global__ void k_count(const int* __restrict__ sel, int* meta) {
  int i = blockIdx.x * 256 + threadIdx.x;
  if (i < NPAIR) atomicAdd(&meta[sel[i]], 1);
}

__global__ void k_scan(int* meta) {
  if (threadIdx.x == 0) {
    int acc = 0, t256 = 0;
    for (int e = 0; e < E_; e++) {
      meta[16 + e] = acc;
      int c = meta[e];
      for (int r0 = 0; r0 < c; r0 += 256) meta[32 + (t256++)] = (e << 13) | r0;
      acc += c;
    }
    meta[24] = acc;
    meta[25] = t256;
  }
}

__global__ void k_fill(const int* __restrict__ sel, const float* __restrict__ probs,
                       int* meta, int* __restrict__ tok, int* __restrict__ slot,
                       float* __restrict__ prob) {
  int i = blockIdx.x * 256 + threadIdx.x;
  if (i < NPAIR) {
    int e = sel[i];
    int pos = meta[16 + e] + atomicAdd(&meta[8 + e], 1);
    tok[pos]  = i & (NTOK - 1);
    slot[pos] = i;
    prob[pos] = probs[i];
  }
}

__global__ void k_gather(const float* __restrict__ x, const int* __restrict__ tok,
                         unsigned short* __restrict__ Xg) {
  int p = blockIdx.x, t = threadIdx.x;
  int token = tok[p];
  float4 v = ((const float4*)(x + (size_t)token * H_))[t];
  ushort4 o;
  o.x = f2bf(v.x); o.y = f2bf(v.y); o.z = f2bf(v.z); o.w = f2bf(v.w);
  ((ushort4*)(Xg + (size_t)p * H_))[t] = o;
}

// src [E][R][C] f32 -> dst [E][C][R] bf16.  64x64 tiles, coalesced ushort2 writes.
__global__ void k_transpose(const float* __restrict__ src, unsigned short* __restrict__ dst,
                            int R, int C) {
  __shared__ float tile[64][65];
  int e = blockIdx.z;
  size_t c0 = (size_t)blockIdx.x * 64, r0 = (size_t)blockIdx.y * 64;
  int t = threadIdx.x;
  int r = t >> 2, q = t & 3;
  const float4* s = (const float4*)(src + ((size_t)e * R + r0 + r) * C + c0 + q * 16);
  float4 v0 = s[0], v1 = s[1], v2 = s[2], v3 = s[3];
  float* tp = &tile[r][q * 16];
  tp[0]=v0.x; tp[1]=v0.y; tp[2]=v0.z; tp[3]=v0.w;
  tp[4]=v1.x; tp[5]=v1.y; tp[6]=v1.z; tp[7]=v1.w;
  tp[8]=v2.x; tp[9]=v2.y; tp[10]=v2.z; tp[11]=v2.w;
  tp[12]=v3.x; tp[13]=v3.y; tp[14]=v3.z; tp[15]=v3.w;
  __syncthreads();
  unsigned short* d = dst + ((size_t)e * C + c0) * R + r0;
#pragma unroll
  for (int i = 0; i < 8; i++) {
    int chunk = t + 256 * i;           // 0..2047
    int c = chunk >> 5, j = chunk & 31;
    ushort2 o;
    o.x = f2bf(tile[2 * j][c]);
    o.y = f2bf(tile[2 * j + 1][c]);
    *(ushort2*)(d + (size_t)c * R + 2 * j) = o;
  }
}

__device__ __forceinline__ float gelu_f(float x) {
  float x2 = x * x;
  float ttt = x * (2.302118f + 0.1029518f * x2);
  ttt = fminf(ttt, 60.f);
  float u = __builtin_amdgcn_exp2f(ttt);
  float rr = __frcp_rn(1.f + u);
  return x * u * rr;
}

// ------- 256x128 grouped GEMM, 4 waves (per-wave 128x64), BK=32 dbuf --------
// Per-wave 128x64 => 42.7 FLOP per LDS-byte (LDS-read ~0.6x MFMA, not bound).
// 48 KB LDS + <=256 VGPR (launch_bounds(256,2)) => 2 blocks/CU for cross-block
// TLP over the per-K-step __syncthreads drain (round-5 proven loop).
// Swizzle involution (round-5 verified, conflicts==0): X(v)=v^(((v>>7)&7)<<4)
// applied to per-lane global source AND ds_read addrs; linear gload_lds dest.
// EP0: Hbuf = gelu(acc+b1) bf16.  EP1 (z-split): yplane[z] = (acc+(z==0)*b2)*prob.
template <int KROW, int KLEN, int EP>
__global__ __launch_bounds__(256, 2) void k_gw(
    const short* __restrict__ Aall, const short* __restrict__ Wt,
    const float* __restrict__ bias, const int* __restrict__ meta,
    unsigned short* __restrict__ Hbuf, float* __restrict__ ybuf,
    const int* __restrict__ slotA, const float* __restrict__ prob) {
  constexpr int NT = KLEN / 32;
  constexpr int NFULL = (EP == 0) ? F_ : H_;
  constexpr int NTMAX = 40;
  __shared__ __align__(1024) char lds[2][24576];   // [buf][A 16K | B 8K]

  int bid = blockIdx.x;
  int q = gridDim.x >> 3;
  int vid = (bid & 7) * q + (bid >> 3);            // bijective XCD chunking
  int x, y, z, koff;
  if (EP == 0) {
    x = vid / NTMAX; y = vid - x * NTMAX; z = 0; koff = 0;
  } else {
    int x2 = vid / NTMAX; y = vid - x2 * NTMAX;
    x = x2 >> 1; z = x2 & 1; koff = z * KLEN;
  }
  if (y >= meta[25]) return;
  int dsc = meta[32 + y];
  int e = dsc >> 13, r0 = dsc & 8191;
  int ne = meta[e];
  int p0 = meta[16 + e] + r0;
  int n0 = x * 128;
  const char* A0 = (const char*)(Aall + (size_t)p0 * KROW + koff);
  const char* B0 = (const char*)(Wt + ((size_t)e * NFULL + n0) * KROW + koff);

  int t = threadIdx.x, lane = t & 63, wid = t >> 6;
  int wr = wid >> 1, wc = wid & 1, g = lane >> 4, l15 = lane & 15;
  f32x4 acc[8][4] = {};

  auto stage = [&](int kt, char* dst) {
#pragma unroll
    for (int l = 0; l < 4; l++) {      // A: 16 KB (256 rows x 64 B)
      int off = l * 4096 + t * 16;
      int o2 = off ^ (((off >> 7) & 7) << 4);
      int row = o2 >> 6, cb = o2 & 63;
      load_lds16(A0 + (size_t)row * (KROW * 2) + kt * 64 + cb, dst + off);
    }
#pragma unroll
    for (int l = 0; l < 2; l++) {      // B: 8 KB (128 rows x 64 B)
      int off = l * 4096 + t * 16;
      int o2 = off ^ (((off >> 7) & 7) << 4);
      int row = o2 >> 6, cb = o2 & 63;
      load_lds16(B0 + (size_t)row * (KROW * 2) + kt * 64 + cb, dst + 16384 + off);
    }
  };

  auto compute = [&](const char* ab) {
    const char* bb = ab + 16384;
    bf16x8 af[8], bf[4];
#pragma unroll
    for (int m = 0; m < 8; m++) {
      int a = (wr * 128 + m * 16 + l15) * 64 + g * 16;
      af[m] = *(const bf16x8*)(ab + (a ^ (((a >> 7) & 7) << 4)));
    }
#pragma unroll
    for (int n = 0; n < 4; n++) {
      int b = (wc * 64 + n * 16 + l15) * 64 + g * 16;
      bf[n] = *(const bf16x8*)(bb + (b ^ (((b >> 7) & 7) << 4)));
    }
    __builtin_amdgcn_s_setprio(1);
#pragma unroll
    for (int m = 0; m < 8; m++)
#pragma unroll
      for (int n = 0; n < 4; n++)
        acc[m][n] = __builtin_amdgcn_mfma_f32_16x16x32_bf16(af[m], bf[n], acc[m][n], 0, 0, 0);
    __builtin_amdgcn_s_setprio(0);
  };

  stage(0, lds[0]);
  __syncthreads();
  int cur = 0;
  for (int kt = 0; kt < NT; kt++) {
    if (kt + 1 < NT) stage(kt + 1, lds[cur ^ 1]);
    compute(lds[cur]);
    __syncthreads();
    cur ^= 1;
  }

  if (EP == 0) {
#pragma unroll
    for (int n = 0; n < 4; n++) {
      int col = n0 + wc * 64 + n * 16 + l15;
      float bv = bias[e * F_ + col];
#pragma unroll
      for (int m = 0; m < 8; m++) {
        int rbase = wr * 128 + m * 16 + g * 4;
#pragma unroll
        for (int r = 0; r < 4; r++) {
          int row = rbase + r;
          if (r0 + row < ne) {
            float xv = acc[m][n][r] + bv;
            Hbuf[(size_t)(p0 + row) * F_ + col] = f2bf(gelu_f(xv));
          }
        }
      }
    }
  } else {
    float* yplane = ybuf + (size_t)z * NPAIR * H_;
#pragma unroll
    for (int n = 0; n < 4; n++) {
      int col = n0 + wc * 64 + n * 16 + l15;
      float bv = (z == 0) ? bias[e * H_ + col] : 0.f;
#pragma unroll
      for (int m = 0; m < 8; m++) {
        int rbase = wr * 128 + m * 16 + g * 4;
#pragma unroll
        for (int r = 0; r < 4; r++) {
          int row = rbase + r;
          if (r0 + row < ne) {
            int p = p0 + row;
            yplane[(size_t)slotA[p] * H_ + col] = (acc[m][n][r] + bv) * prob[p];
          }
        }
      }
    }
  }
}

__global__ void k_combine(const float* __restrict__ yb, float* __restrict__ out) {
  size_t i = (size_t)blockIdx.x * 256 + threadIdx.x;
  const float4* p00 = (const float4*)yb;                                   // z0,k0
  const float4* p01 = (const float4*)(yb + (size_t)NTOK * H_);             // z0,k1
  const float4* p10 = (const float4*)(yb + (size_t)NPAIR * H_);            // z1,k0
  const float4* p11 = (const float4*)(yb + (size_t)NPAIR * H_ + (size_t)NTOK * H_);
  float4 a = p00[i], b = p01[i], c = p10[i], d = p11[i];
  float4 o;
  o.x = a.x + b.x + c.x + d.x;
  o.y = a.y + b.y + c.y + d.y;
  o.z = a.z + b.z + c.z + d.z;
  o.w = a.w + b.w + c.w + d.w;
  ((float4*)out)[i] = o;
}

extern "C" void kernel_launch(void* const* d_in, const int* in_sizes, int n_in,
                              void* d_out, int out_size, void* d_ws, size_t ws_size,
                              hipStream_t stream) {
  const float* x     = (const float*)d_in[0];
  const float* probs = (const float*)d_in[1];
  const int*   sel   = (const int*)d_in[2];
  const float* w1    = (const float*)d_in[3];
  const float* b1    = (const float*)d_in[4];
  const float* w2    = (const float*)d_in[5];
  const float* b2    = (const float*)d_in[6];
  float* out = (float*)d_out;

  char* W = (char*)d_ws;
  int*   meta = (int*)W;
  int*   tok  = (int*)(W + 4096);
  int*   slot = (int*)(W + 36864);
  float* prob = (float*)(W + 69632);
  unsigned short* Xg  = (unsigned short*)(W + WS_XG);
  short* w1t = (short*)(W + WS_W1T);
  short* w2t = (short*)(W + WS_W2T);
  unsigned short* Hb  = (unsigned short*)(W + WS_HBUF);
  float* yb  = (float*)(W + WS_YBUF);

  k_init<<<1, 256, 0, stream>>>(meta);
  k_count<<<NPAIR / 256, 256, 0, stream>>>(sel, meta);
  k_scan<<<1, 64, 0, stream>>>(meta);
  k_fill<<<NPAIR / 256, 256, 0, stream>>>(sel, probs, meta, tok, slot, prob);
  k_gather<<<NPAIR, 256, 0, stream>>>(x, tok, Xg);
  k_transpose<<<dim3(F_ / 64, H_ / 64, E_), 256, 0, stream>>>(w1, (unsigned short*)w1t, H_, F_);
  k_transpose<<<dim3(H_ / 64, F_ / 64, E_), 256, 0, stream>>>(w2, (unsigned short*)w2t, F_, H_);
  // GEMM1: 256x128 tile, K=1024, flat grid 32 cols x 40 tiles = 1280
  k_gw<H_, H_, 0><<<32 * 40, 256, 0, stream>>>(
      (const short*)Xg, w1t, b1, meta, Hb, yb, slot, prob);
  // GEMM2: 256x128 tile, K=4096 z-split in 2 (KLEN=2048), grid 8 x 2 x 40 = 640
  k_gw<F_, F_ / 2, 1><<<8 * 2 * 40, 256, 0, stream>>>(
      (const short*)Hb, w2t, b2, meta, Hb, yb, slot, prob);
  k_combine<<<(NTOK * H_ / 4) / 256, 256, 0, stream>>>(yb, out);
}

// Round 8
// 454.075 us; speedup vs baseline: 4.9174x; 1.1559x over previous
//
#include <hip/hip_runtime.h>
#include <hip/hip_bf16.h>
#include <stdint.h>

#define B_ 2
#define S_ 2048
#define H_ 1024
#define F_ 4096
#define E_ 8
#define KTOP_ 2
#define NTOK (B_*S_)          // 4096
#define NPAIR (KTOP_*NTOK)    // 8192
#define NPAIR_PAD (NPAIR+256)

// ---- workspace layout (bytes) ----
static const size_t WS_XG   = 131072;
static const size_t SZ_XG   = (size_t)NPAIR_PAD * H_ * 2;
static const size_t WS_W1T  = WS_XG + SZ_XG;
static const size_t SZ_W1T  = (size_t)E_ * F_ * H_ * 2;
static const size_t WS_W2T  = WS_W1T + SZ_W1T;
static const size_t SZ_W2T  = (size_t)E_ * H_ * F_ * 2;
static const size_t WS_HBUF = WS_W2T + SZ_W2T;
static const size_t SZ_HBUF = (size_t)NPAIR_PAD * F_ * 2;
static const size_t WS_YBUF = WS_HBUF + SZ_HBUF;

typedef __attribute__((ext_vector_type(8))) short bf16x8;
typedef __attribute__((ext_vector_type(4))) float f32x4;

__device__ __forceinline__ unsigned short f2bf(float f) {
  unsigned int u = __float_as_uint(f);
  u += 0x7fffu + ((u >> 16) & 1u);
  return (unsigned short)(u >> 16);
}

__device__ __forceinline__ void load_lds16(const void* g, void* l) {
  __builtin_amdgcn_global_load_lds(
      (const __attribute__((address_space(1))) unsigned int*)g,
      (__attribute__((address_space(3))) unsigned int*)l, 16, 0, 0);
}

// meta ints: [0..7]=counts [8..15]=fill [16..23]=offs [24]=total
// [26]=ntiles128 [72..151]=desc128
__global__ void k_init(int* meta) {
  if (threadIdx.x < 32) meta[threadIdx.x] = 0;
}

__global__ void k_count(const int* __restrict__ sel, int* meta) {
  int i = blockIdx.x * 256 + threadIdx.x;
  if (i < NPAIR) atomicAdd(&meta[sel[i]], 1);
}

__global__ void k_scan(int* meta) {
  if (threadIdx.x == 0) {
    int acc = 0, t128 = 0;
    for (int e = 0; e < E_; e++) {
      meta[16 + e] = acc;
      int c = meta[e];
      for (int r0 = 0; r0 < c; r0 += 128) meta[72 + (t128++)] = (e << 13) | r0;
      acc += c;
    }
    meta[24] = acc;
    meta[26] = t128;
  }
}

__global__ void k_fill(const int* __restrict__ sel, const float* __restrict__ probs,
                       int* meta, int* __restrict__ tok, int* __restrict__ slot,
                       float* __restrict__ prob) {
  int i = blockIdx.x * 256 + threadIdx.x;
  if (i < NPAIR) {
    int e = sel[i];
    int pos = meta[16 + e] + atomicAdd(&meta[8 + e], 1);
    tok[pos]  = i & (NTOK - 1);
    slot[pos] = i;
    prob[pos] = probs[i];
  }
}

__global__ void k_gather(const float* __restrict__ x, const int* __restrict__ tok,
                         unsigned short* __restrict__ Xg) {
  int p = blockIdx.x, t = threadIdx.x;
  int token = tok[p];
  float4 v = ((const float4*)(x + (size_t)token * H_))[t];
  ushort4 o;
  o.x = f2bf(v.x); o.y = f2bf(v.y); o.z = f2bf(v.z); o.w = f2bf(v.w);
  ((ushort4*)(Xg + (size_t)p * H_))[t] = o;
}

// src [E][R][C] f32 -> dst [E][C][R] bf16.  64x64 tiles, coalesced ushort2 writes.
__global__ void k_transpose(const float* __restrict__ src, unsigned short* __restrict__ dst,
                            int R, int C) {
  __shared__ float tile[64][65];
  int e = blockIdx.z;
  size_t c0 = (size_t)blockIdx.x * 64, r0 = (size_t)blockIdx.y * 64;
  int t = threadIdx.x;
  int r = t >> 2, q = t & 3;
  const float4* s = (const float4*)(src + ((size_t)e * R + r0 + r) * C + c0 + q * 16);
  float4 v0 = s[0], v1 = s[1], v2 = s[2], v3 = s[3];
  float* tp = &tile[r][q * 16];
  tp[0]=v0.x; tp[1]=v0.y; tp[2]=v0.z; tp[3]=v0.w;
  tp[4]=v1.x; tp[5]=v1.y; tp[6]=v1.z; tp[7]=v1.w;
  tp[8]=v2.x; tp[9]=v2.y; tp[10]=v2.z; tp[11]=v2.w;
  tp[12]=v3.x; tp[13]=v3.y; tp[14]=v3.z; tp[15]=v3.w;
  __syncthreads();
  unsigned short* d = dst + ((size_t)e * C + c0) * R + r0;
#pragma unroll
  for (int i = 0; i < 8; i++) {
    int chunk = t + 256 * i;           // 0..2047
    int c = chunk >> 5, j = chunk & 31;
    ushort2 o;
    o.x = f2bf(tile[2 * j][c]);
    o.y = f2bf(tile[2 * j + 1][c]);
    *(ushort2*)(d + (size_t)c * R + 2 * j) = o;
  }
}

__device__ __forceinline__ float gelu_f(float x) {
  float x2 = x * x;
  float ttt = x * (2.302118f + 0.1029518f * x2);
  ttt = fminf(ttt, 60.f);
  float u = __builtin_amdgcn_exp2f(ttt);
  float rr = __frcp_rn(1.f + u);
  return x * u * rr;
}

// --------- R5-proven grouped GEMM: 128x128, BK=32, dbuf, 4 waves ------------
// ONLY change vs round 5: flat grid + per-XCD x-band mapping.
//   xcd = bid & 7; i = bid >> 3; x = xcd*XPX + (i & (XPX-1)); y = i >> LOGXPX
// Each XCD keeps its XPX B-panels L2-resident (<=1 MB) and reuses each
// A-panel across its XPX consecutive x-blocks -> staging served by L2
// (34 TB/s) instead of L3/fabric (~7.4 TB/s ceiling identified R1-R7).
template <int K, int EP, int XPX, int LOGXPX>
__global__ __launch_bounds__(256, 4) void k_gemmdb(
    const short* __restrict__ Aall, const short* __restrict__ Wt,
    const float* __restrict__ bias, const int* __restrict__ meta,
    unsigned short* __restrict__ Hbuf, float* __restrict__ ybuf,
    const int* __restrict__ slotA, const float* __restrict__ prob) {
  constexpr int NT = K / 32;
  constexpr int NFULL = (EP == 0) ? F_ : H_;
  __shared__ __align__(1024) char lds[2][16384];   // [buf][A 8K | B 8K]

  int bid = blockIdx.x;
  int xcd = bid & 7, i = bid >> 3;
  int x = (xcd << LOGXPX) + (i & (XPX - 1));
  int y = i >> LOGXPX;
  if (y >= meta[26]) return;
  int dsc = meta[72 + y];
  int e = dsc >> 13, r0 = dsc & 8191;
  int ne = meta[e];
  int p0 = meta[16 + e] + r0;
  int n0 = x * 128;
  const char* A0 = (const char*)(Aall + (size_t)p0 * K);
  const char* B0 = (const char*)(Wt + ((size_t)e * NFULL + n0) * K);

  int t = threadIdx.x, lane = t & 63, wid = t >> 6;
  int wr = wid >> 1, wc = wid & 1, g = lane >> 4, l15 = lane & 15;
  f32x4 acc[4][4] = {};

  auto stage = [&](int kt, char* dst) {
#pragma unroll
    for (int l = 0; l < 2; l++) {      // A: 2 chunks/thread
      int off = l * 4096 + t * 16;
      int o2 = off ^ (((off >> 7) & 7) << 4);
      int row = o2 >> 6, cb = o2 & 63;
      load_lds16(A0 + (size_t)row * (K * 2) + kt * 64 + cb, dst + off);
    }
#pragma unroll
    for (int l = 0; l < 2; l++) {      // B: 2 chunks/thread
      int off = l * 4096 + t * 16;
      int o2 = off ^ (((off >> 7) & 7) << 4);
      int row = o2 >> 6, cb = o2 & 63;
      load_lds16(B0 + (size_t)row * (K * 2) + kt * 64 + cb, dst + 8192 + off);
    }
  };

  auto compute = [&](const char* ab) {
    const char* bb = ab + 8192;
    bf16x8 af[4], bf[4];
#pragma unroll
    for (int m = 0; m < 4; m++) {
      int a = (wr * 64 + m * 16 + l15) * 64 + g * 16;
      af[m] = *(const bf16x8*)(ab + (a ^ (((a >> 7) & 7) << 4)));
    }
#pragma unroll
    for (int n = 0; n < 4; n++) {
      int b = (wc * 64 + n * 16 + l15) * 64 + g * 16;
      bf[n] = *(const bf16x8*)(bb + (b ^ (((b >> 7) & 7) << 4)));
    }
    __builtin_amdgcn_s_setprio(1);
#pragma unroll
    for (int m = 0; m < 4; m++)
#pragma unroll
      for (int n = 0; n < 4; n++)
        acc[m][n] = __builtin_amdgcn_mfma_f32_16x16x32_bf16(af[m], bf[n], acc[m][n], 0, 0, 0);
    __builtin_amdgcn_s_setprio(0);
  };

  stage(0, lds[0]);
  __syncthreads();
  int cur = 0;
  for (int kt = 0; kt < NT; kt++) {
    if (kt + 1 < NT) stage(kt + 1, lds[cur ^ 1]);
    compute(lds[cur]);
    __syncthreads();
    cur ^= 1;
  }

  if (EP == 0) {
#pragma unroll
    for (int n = 0; n < 4; n++) {
      int col = n0 + wc * 64 + n * 16 + l15;
      float bv = bias[e * F_ + col];
#pragma unroll
      for (int m = 0; m < 4; m++) {
        int rbase = wr * 64 + m * 16 + g * 4;
#pragma unroll
        for (int r = 0; r < 4; r++) {
          int row = rbase + r;
          if (r0 + row < ne) {
            float xv = acc[m][n][r] + bv;
            Hbuf[(size_t)(p0 + row) * F_ + col] = f2bf(gelu_f(xv));
          }
        }
      }
    }
  } else {
#pragma unroll
    for (int n = 0; n < 4; n++) {
      int col = n0 + wc * 64 + n * 16 + l15;
      float bv = bias[e * H_ + col];
#pragma unroll
      for (int m = 0; m < 4; m++) {
        int rbase = wr * 64 + m * 16 + g * 4;
#pragma unroll
        for (int r = 0; r < 4; r++) {
          int row = rbase + r;
          if (r0 + row < ne) {
            int p = p0 + row;
            ybuf[(size_t)slotA[p] * H_ + col] = (acc[m][n][r] + bv) * prob[p];
          }
        }
      }
    }
  }
}

__global__ void k_combine(const float* __restrict__ yb, float* __restrict__ out) {
  size_t i = (size_t)blockIdx.x * 256 + threadIdx.x;
  float4 a = ((const float4*)yb)[i];
  float4 b = ((const float4*)(yb + (size_t)NTOK * H_))[i];
  float4 o;
  o.x = a.x + b.x; o.y = a.y + b.y; o.z = a.z + b.z; o.w = a.w + b.w;
  ((float4*)out)[i] = o;
}

extern "C" void kernel_launch(void* const* d_in, const int* in_sizes, int n_in,
                              void* d_out, int out_size, void* d_ws, size_t ws_size,
                              hipStream_t stream) {
  const float* x     = (const float*)d_in[0];
  const float* probs = (const float*)d_in[1];
  const int*   sel   = (const int*)d_in[2];
  const float* w1    = (const float*)d_in[3];
  const float* b1    = (const float*)d_in[4];
  const float* w2    = (const float*)d_in[5];
  const float* b2    = (const float*)d_in[6];
  float* out = (float*)d_out;

  char* W = (char*)d_ws;
  int*   meta = (int*)W;
  int*   tok  = (int*)(W + 4096);
  int*   slot = (int*)(W + 36864);
  float* prob = (float*)(W + 69632);
  unsigned short* Xg  = (unsigned short*)(W + WS_XG);
  short* w1t = (short*)(W + WS_W1T);
  short* w2t = (short*)(W + WS_W2T);
  unsigned short* Hb  = (unsigned short*)(W + WS_HBUF);
  float* yb  = (float*)(W + WS_YBUF);

  k_init<<<1, 256, 0, stream>>>(meta);
  k_count<<<NPAIR / 256, 256, 0, stream>>>(sel, meta);
  k_scan<<<1, 64, 0, stream>>>(meta);
  k_fill<<<NPAIR / 256, 256, 0, stream>>>(sel, probs, meta, tok, slot, prob);
  k_gather<<<NPAIR, 256, 0, stream>>>(x, tok, Xg);
  k_transpose<<<dim3(F_ / 64, H_ / 64, E_), 256, 0, stream>>>(w1, (unsigned short*)w1t, H_, F_);
  k_transpose<<<dim3(H_ / 64, F_ / 64, E_), 256, 0, stream>>>(w2, (unsigned short*)w2t, F_, H_);
  // GEMM1: 128x128 BK=32 dbuf; flat grid 32x72, XPX=4 (4 N-cols per XCD)
  k_gemmdb<H_, 0, 4, 2><<<32 * 72, 256, 0, stream>>>(
      (const short*)Xg, w1t, b1, meta, Hb, yb, slot, prob);
  // GEMM2: 128x128 BK=32 dbuf; flat grid 8x72, XPX=1 (1 N-col per XCD)
  k_gemmdb<F_, 1, 1, 0><<<8 * 72, 256, 0, stream>>>(
      (const short*)Hb, w2t, b2, meta, Hb, yb, slot, prob);
  k_combine<<<(NTOK * H_ / 4) / 256, 256, 0, stream>>>(yb, out);
}